// Round 10
// baseline (1907.610 us; speedup 1.0000x reference)
//
#include <hip/hip_runtime.h>
#include <stdint.h>

// Bidirectional LSTM.  B=32, T=512, V=32000, D=300, U=300, NT=3.
// R23 = R21/R22 base + TAGGED-WORD PUBLISH (drain+flag deleted).
// R22's diagnostic: FETCH identical to R21 -> poll almost never re-iterates ->
// flag already visible at first sample -> chain is producer drain (1RT) +
// flag hop (0.5RT), not consumer latency.  Fix: u64 [tag|2xbf16] words,
// tag=ts+1, parity double-buffer.  Producer publishes DIRECT from registers
// after gates (partner bf16 via shfl_xor(.,4)); no drain, no barrier(3),
// no flag.  Consumer: R22-style fused poll on its 19 words, scatter OUT of
// the loop, no sleep.  Tag travels atomically with payload -> no fences.
// R14's failure modes addressed: in-loop scatter (bank conflicts), sleep
// quantization, publish-after-barrier -- all removed here.
// History: R13=2065/rec1751, R19=1823/rec1509, R21=1723/rec1509,
// R22=1719/rec1501 (revert target).

#define BB 32
#define TT 512
#define DD 300
#define UU 300
#define G4 1200   // 4*U
#define NTOK 3

#define KB   10    // rec blocks per direction
#define UPB  30    // units per rec block
#define NCOL 120   // gate-cols per rec block (4*UPB)
#define KTILES 10  // K = 320 (300 padded), 10 tiles of 32
#define HSTR 320   // swizzled LDS row stride (elems)
#define HROW 304   // WrPT k-stride (elems, k>=300 zero)

#define WKROWS 1280  // WkT padded p-rows
#define WKSTR  320   // WkT padded k-stride

#define WPR  150           // tagged words per batch row (2 units each)
#define WBUF (BB * WPR)    // 4800 words per parity buffer per dir
#define PW   19            // polled words per thread (ceil(4800/256))

typedef uint16_t bf16_t;
typedef short  s16x8 __attribute__((ext_vector_type(8)));
typedef float  f32x4 __attribute__((ext_vector_type(4)));

union U8 { unsigned long long q[2]; s16x8 v; };

__device__ __forceinline__ float bf2f(uint16_t u) {
    union { uint32_t i; float f; } v; v.i = ((uint32_t)u) << 16; return v.f;
}
__device__ __forceinline__ uint16_t f2bf(float f) {
    union { uint32_t i; float f; } v; v.f = f;
    uint32_t r = v.i + 0x7fffu + ((v.i >> 16) & 1u);   // RNE
    return (uint16_t)(r >> 16);
}
__device__ __forceinline__ float ldf(const void* base, size_t idx, int f32m) {
    return f32m ? ((const float*)base)[idx]
                : bf2f(((const uint16_t*)base)[idx]);
}

// 4x4 transpose across lane bits 0..1 (verified R7)
__device__ __forceinline__ f32x4 xpose4(f32x4 v, int lane) {
    f32x4 t, w, s, r;
    t[0] = __shfl_xor(v[0], 1); t[1] = __shfl_xor(v[1], 1);
    t[2] = __shfl_xor(v[2], 1); t[3] = __shfl_xor(v[3], 1);
    if ((lane & 1) == 0) { w[0]=v[0]; w[1]=t[0]; w[2]=v[2]; w[3]=t[2]; }
    else                 { w[0]=t[1]; w[1]=v[1]; w[2]=t[3]; w[3]=v[3]; }
    s[0] = __shfl_xor(w[0], 2); s[1] = __shfl_xor(w[1], 2);
    s[2] = __shfl_xor(w[2], 2); s[3] = __shfl_xor(w[3], 2);
    if ((lane & 2) == 0) { r[0]=w[0]; r[1]=w[1]; r[2]=s[0]; r[3]=s[1]; }
    else                 { r[0]=s[2]; r[1]=s[3]; r[2]=w[2]; r[3]=w[3]; }
    return r;
}

// fast sigmoid/tanh: v_exp + v_rcp (rel err ~1e-6, margin 6x vs threshold)
__device__ __forceinline__ float fsig(float x) {
    return __builtin_amdgcn_rcpf(1.f + __expf(-x));
}
__device__ __forceinline__ float ftanh(float x) {
    float cx = fminf(10.f, fmaxf(-10.f, x));
    float e = __expf(2.f * cx);
    return (e - 1.f) * __builtin_amdgcn_rcpf(e + 1.f);
}

__device__ __forceinline__ void gatefn(f32x4 zv, uint2 zp, bool m,
                                       float& c, float& h) {
    float zi = zv[0] + bf2f((uint16_t)(zp.x & 0xffff));
    float zf = zv[1] + bf2f((uint16_t)(zp.x >> 16));
    float zg = zv[2] + bf2f((uint16_t)(zp.y & 0xffff));
    float zo = zv[3] + bf2f((uint16_t)(zp.y >> 16));
    float si = fsig(zi);
    float sf = fsig(zf);
    float so = fsig(zo);
    float tg = ftanh(zg);
    float cn = sf * c + si * tg;
    float hn = so * ftanh(cn);
    if (m) { c = cn; h = hn; }
}

// ---------------------------------------------------------------------------
// Kernel 0: dtype detector (f32 vs bf16 inputs).
// ---------------------------------------------------------------------------
__global__ void detect_dtype(const uint16_t* __restrict__ emb_u16,
                             int* __restrict__ flag) {
    __shared__ float red[256];
    const int tid = threadIdx.x;
    float m = 0.f;
    for (int k = tid; k < 4096; k += 256)
        m = fmaxf(m, fabsf(bf2f(emb_u16[2 * k])));
    red[tid] = m;
    __syncthreads();
    for (int s = 128; s > 0; s >>= 1) {
        if (tid < s) red[tid] = fmaxf(red[tid], red[tid + s]);
        __syncthreads();
    }
    if (tid == 0) flag[0] = (red[0] > 1.0e3f) ? 1 : 0;
}

// ---------------------------------------------------------------------------
// Kernel 1: build WrPT[dir][p][k] (rec weights): p = 4u+g, k-major rows of
// length 304 (k>=300 zero).  WrPT[p][k] = Wr[k][g*300+u].
// ---------------------------------------------------------------------------
__global__ void prep_wrp(const void* __restrict__ Wr_f,
                         const void* __restrict__ Wr_b,
                         bf16_t* __restrict__ WrPT_f,
                         bf16_t* __restrict__ WrPT_b,
                         const int* __restrict__ flagp) {
    const int f32m = *flagp;
    int idx = blockIdx.x * 256 + threadIdx.x;          // over 1200*304
    const void* src = blockIdx.y ? Wr_b : Wr_f;
    bf16_t*     dst = blockIdx.y ? WrPT_b : WrPT_f;
    if (idx < G4 * HROW) {
        int p = idx / HROW;
        int k = idx - p * HROW;
        int u = p >> 2, g = p & 3;
        float v = (k < DD) ? ldf(src, (size_t)k * G4 + g * UU + u, f32m) : 0.f;
        dst[idx] = f2bf(v);
    }
}

// ---------------------------------------------------------------------------
// Kernel 1c: build WkT[dir][p][k] (zx weights, permuted+padded) + biasP.
// ---------------------------------------------------------------------------
__global__ void prep_wkt(const void* __restrict__ Wk_f, const void* __restrict__ b_f,
                         const void* __restrict__ Wk_b, const void* __restrict__ b_b,
                         bf16_t* __restrict__ WkT, bf16_t* __restrict__ biasP,
                         const int* __restrict__ flagp) {
    const int f32m = *flagp;
    const int dir = blockIdx.y;
    const void* Wk = dir ? Wk_b : Wk_f;
    const void* bs = dir ? b_b  : b_f;
    bf16_t* dst = WkT + (size_t)dir * (WKROWS * WKSTR);
    int idx = blockIdx.x * 256 + threadIdx.x;          // over 1280*320
    if (idx < WKROWS * WKSTR) {
        int p = idx / WKSTR;
        int k = idx - p * WKSTR;
        int u = p >> 2, g = p & 3;
        float v = (p < G4 && k < DD) ? ldf(Wk, (size_t)k * G4 + g * UU + u, f32m)
                                     : 0.f;
        dst[idx] = f2bf(v);
        if (idx < WKROWS) {
            int pp = idx, uu = pp >> 2, gg = pp & 3;
            biasP[dir * WKROWS + idx] =
                (pp < G4) ? f2bf(ldf(bs, gg * UU + uu, f32m)) : (bf16_t)0;
        }
    }
}

// ---------------------------------------------------------------------------
// Kernel 1b: zero tagged-word buffers (tag 0 != any step tag 1..511).
// ---------------------------------------------------------------------------
__global__ void init_state(unsigned long long* __restrict__ Hw) {
    int i = blockIdx.x * 256 + threadIdx.x;
    if (i < 2 * 2 * WBUF) Hw[i] = 0ull;
}

// ---------------------------------------------------------------------------
// Kernel 2: MFMA zx GEMM, A staged ONCE (R21-verbatim).
// ---------------------------------------------------------------------------
#define ZM 64
#define ZN 128
__global__ __launch_bounds__(256, 2) void zx_gemm3(
    const int* __restrict__ inputs, const void* __restrict__ emb,
    const bf16_t* __restrict__ WkTall, const bf16_t* __restrict__ biasP,
    bf16_t* __restrict__ zxf, bf16_t* __restrict__ zxb,
    const int* __restrict__ flagp) {

    const int f32m = *flagp;
    const int dir = blockIdx.y;
    const bf16_t* WkT = WkTall + (size_t)dir * (WKROWS * WKSTR);
    const bf16_t* bp  = biasP + dir * WKROWS;
    bf16_t* out = dir ? zxb : zxf;

    const int tid = threadIdx.x;
    const int rowBase = blockIdx.x * ZM;

    __shared__ __align__(16) uint16_t Alds[ZM * HSTR];   // 40,960 B
    __shared__ int rowids[ZM];

    if (tid < ZM) rowids[tid] = inputs[rowBase + tid];
    for (int i = tid; i < ZM * HSTR; i += 256) Alds[i] = 0;
    __syncthreads();

    // stage A gathered ONCE: 64 rows x 38 groups of 8, swizzled
    for (int i = tid; i < ZM * 38; i += 256) {
        int r = i / 38, g = i - 38 * r;
        int k0 = g * 8;
        const size_t eb = (size_t)rowids[r] * DD + k0;
        uint16_t tmp[8];
        if (g < 37) {
            if (f32m) {
                const float* ef = (const float*)emb + eb;
#pragma unroll
                for (int e = 0; e < 8; e++) tmp[e] = f2bf(ef[e]);
            } else {
                *(uint4*)tmp = *(const uint4*)((const uint16_t*)emb + eb);
            }
        } else {
#pragma unroll
            for (int e = 0; e < 8; e++) {
                int k = k0 + e;
                tmp[e] = (k < DD)
                    ? (f32m ? f2bf(((const float*)emb)[(size_t)rowids[r] * DD + k])
                            : ((const uint16_t*)emb)[(size_t)rowids[r] * DD + k])
                    : (uint16_t)0;
            }
        }
        *(uint4*)&Alds[r * HSTR + ((g ^ (r & 7)) << 3)] = *(uint4*)tmp;
    }
    __syncthreads();

    const int lane = tid & 63;
    const int wv   = tid >> 6;
    const int q    = lane >> 4;
    const int c16  = lane & 15;
    const int n0   = 32 * wv;
    const int sw7  = c16 & 7;
    const bool evn = ((lane & 1) == 0);

    for (int nt = 0; nt < 10; nt++) {
        const int pb = nt * ZN;
        const int p0 = pb + n0 + c16;
        const int p1 = p0 + 16;
        const float bv0 = bf2f(bp[p0]);
        const float bv1 = bf2f(bp[p1]);

        f32x4 acc[4][2];
#pragma unroll
        for (int mt = 0; mt < 4; mt++)
            for (int nh = 0; nh < 2; nh++) acc[mt][nh] = (f32x4){0.f,0.f,0.f,0.f};

#pragma unroll
        for (int kt = 0; kt < KTILES; kt++) {
            int k0 = 32 * kt + 8 * q;
            int sw = (((kt * 4 + q) ^ sw7) << 3);
            s16x8 b0 = *(const s16x8*)&WkT[(size_t)p0 * WKSTR + k0];
            s16x8 b1 = *(const s16x8*)&WkT[(size_t)p1 * WKSTR + k0];
#pragma unroll
            for (int mt = 0; mt < 4; mt++) {
                s16x8 af = *(const s16x8*)&Alds[(16 * mt + c16) * HSTR + sw];
                acc[mt][0] = __builtin_amdgcn_mfma_f32_16x16x32_bf16(af, b0, acc[mt][0], 0, 0, 0);
                acc[mt][1] = __builtin_amdgcn_mfma_f32_16x16x32_bf16(af, b1, acc[mt][1], 0, 0, 0);
            }
        }

        // epilogue: bias add, bf16, pair-pack via shfl_xor(1), even-lane u32
#pragma unroll
        for (int mt = 0; mt < 4; mt++) {
#pragma unroll
            for (int nh = 0; nh < 2; nh++) {
                const int p = (nh == 0) ? p0 : p1;
                const float bv = (nh == 0) ? bv0 : bv1;
#pragma unroll
                for (int r = 0; r < 4; r++) {
                    uint32_t mine = f2bf(acc[mt][nh][r] + bv);
                    uint32_t other = (uint32_t)__shfl_xor((int)mine, 1);
                    if (evn && p < G4) {
                        uint32_t pk = mine | (other << 16);
                        int row = rowBase + 16 * mt + 4 * q + r;
                        *(uint32_t*)&out[(size_t)row * G4 + p] = pk;
                    }
                }
            }
        }
    }
}

// ---------------------------------------------------------------------------
// Kernel 3: MFMA recurrence with tagged-word exchange.  20 blocks, 256 thr.
// Per step: fused poll on self-validating words -> scatter (out of loop) ->
// barrier -> MFMA -> gates -> publish DIRECT from registers (no drain/flag)
// -> hstage -> barrier -> coalesced hout.  2 barriers/step.
// ---------------------------------------------------------------------------
__global__ __launch_bounds__(256, 1) void lstm_rec8(
    const bf16_t* __restrict__ zxf, const bf16_t* __restrict__ zxb,
    const bf16_t* __restrict__ WrPT_f, const bf16_t* __restrict__ WrPT_b,
    const int* __restrict__ seqlen,
    unsigned long long* __restrict__ Hw,
    bf16_t* __restrict__ hf, bf16_t* __restrict__ hb) {

    const int blk = blockIdx.x % KB;
    const int dir = blockIdx.x / KB;
    const bf16_t* zx   = dir ? zxb    : zxf;
    const bf16_t* WrPT = dir ? WrPT_b : WrPT_f;
    bf16_t*       hout = dir ? hb : hf;
    unsigned long long* const Hwd = Hw + (size_t)dir * (2 * WBUF);

    __shared__ __align__(16) uint16_t Hlds[BB * HSTR];    // 20,480 B
    __shared__ uint16_t hstage[BB * UPB];                 //  1,920 B

    const int tid  = threadIdx.x;
    const int lane = tid & 63;
    const int wv   = tid >> 6;
    const int q    = lane >> 4;
    const int c16  = lane & 15;
    const int n0   = 32 * wv;
    const int sw7  = c16 & 7;
    const int k4   = c16 >> 2;
    const int j4   = c16 & 3;
    const int u0   = 8 * wv + k4;
    const int b0   = 4 * q + j4;
    const bool v1  = (u0 + 4 < UPB);

    // fixed per-thread poll-word list: global word W -> swizzled LDS elem.
    // W = b*150 + w ; word w covers units (2w, 2w+1) of batch row b.
    int Wl[PW], El[PW];
#pragma unroll
    for (int m = 0; m < PW; ++m) {
        int W = tid + 256 * m;
        if (W >= WBUF) W = tid;                 // harmless duplicate
        int b = W / WPR, w = W - WPR * b;
        int u = 2 * w, g = u >> 3;
        Wl[m] = W;
        El[m] = b * HSTR + ((g ^ (b & 7)) << 3) + (u & 7);
    }

    // one-time: zero Hlds (ts=0 uses it as H=0), B-frags to regs
    for (int i = tid; i < BB * HSTR; i += 256) Hlds[i] = 0;
    U8 Bf0[KTILES], Bf1[KTILES];
#pragma unroll
    for (int kt = 0; kt < KTILES; kt++) {
        int k0 = 32 * kt + 8 * q;
        int col0 = n0 + c16, col1 = n0 + 16 + c16;
        U8 z; z.q[0] = 0; z.q[1] = 0;
        Bf0[kt] = z; Bf1[kt] = z;
        if (k0 < 304) {
            if (col0 < NCOL)
                Bf0[kt].v = *(const s16x8*)&WrPT[(size_t)(NCOL * blk + col0) * HROW + k0];
            if (col1 < NCOL)
                Bf1[kt].v = *(const s16x8*)&WrPT[(size_t)(NCOL * blk + col1) * HROW + k0];
        }
    }
    float c00 = 0.f, c01 = 0.f, c10 = 0.f, c11 = 0.f;
    float h00 = 0.f, h01 = 0.f, h10 = 0.f, h11 = 0.f;
    const int L0 = seqlen[b0];
    const int L1 = seqlen[b0 + 16];
    __syncthreads();

    for (int ts = 0; ts < TT; ts++) {
        const int t = dir ? (TT - 1 - ts) : ts;

        // zx prefetch (overlaps the poll)
        const size_t zr0 = ((size_t)(b0 * TT + t)) * G4 + NCOL * blk;
        const size_t zr1 = ((size_t)((b0 + 16) * TT + t)) * G4 + NCOL * blk;
        uint2 z00 = *(const uint2*)&zx[zr0 + 4 * u0];
        uint2 z10 = *(const uint2*)&zx[zr1 + 4 * u0];
        uint2 z01 = {0, 0}, z11 = {0, 0};
        if (v1) {
            z01 = *(const uint2*)&zx[zr0 + 4 * (u0 + 4)];
            z11 = *(const uint2*)&zx[zr1 + 4 * (u0 + 4)];
        }

        // fused poll on tagged words; detecting loads carry the payload.
        if (ts > 0) {
            const unsigned long long* const src = Hwd + (size_t)(ts & 1) * WBUF;
            const uint32_t tagv = (uint32_t)ts;
            unsigned long long hv[PW];
            for (;;) {
#pragma unroll
                for (int m = 0; m < PW; ++m)
                    hv[m] = __hip_atomic_load(&src[Wl[m]], __ATOMIC_RELAXED,
                                              __HIP_MEMORY_SCOPE_AGENT);
                bool ok = true;
#pragma unroll
                for (int m = 0; m < PW; ++m)
                    ok &= ((uint32_t)(hv[m] >> 32) == tagv);
                if (__all(ok)) {
#pragma unroll
                    for (int m = 0; m < PW; ++m)
                        *(uint32_t*)&Hlds[El[m]] = (uint32_t)hv[m];
                    break;
                }
            }
        }
        __syncthreads();                                  // (1)

        // MFMA: A from Hlds (swizzled), B from registers
        f32x4 acc00 = {0.f,0.f,0.f,0.f}, acc01 = {0.f,0.f,0.f,0.f};
        f32x4 acc10 = {0.f,0.f,0.f,0.f}, acc11 = {0.f,0.f,0.f,0.f};
#pragma unroll
        for (int kt = 0; kt < KTILES; kt++) {
            int sw = (((kt * 4 + q) ^ sw7) << 3);
            s16x8 a0 = *(const s16x8*)&Hlds[c16 * HSTR + sw];
            s16x8 a1 = *(const s16x8*)&Hlds[(c16 + 16) * HSTR + sw];
            acc00 = __builtin_amdgcn_mfma_f32_16x16x32_bf16(a0, Bf0[kt].v, acc00, 0, 0, 0);
            acc01 = __builtin_amdgcn_mfma_f32_16x16x32_bf16(a0, Bf1[kt].v, acc01, 0, 0, 0);
            acc10 = __builtin_amdgcn_mfma_f32_16x16x32_bf16(a1, Bf0[kt].v, acc10, 0, 0, 0);
            acc11 = __builtin_amdgcn_mfma_f32_16x16x32_bf16(a1, Bf1[kt].v, acc11, 0, 0, 0);
        }

        // transpose + gates in registers (R7-verified mapping)
        f32x4 t00 = xpose4(acc00, lane);
        f32x4 t01 = xpose4(acc01, lane);
        f32x4 t10 = xpose4(acc10, lane);
        f32x4 t11 = xpose4(acc11, lane);
        const bool m0 = (t < L0);
        const bool m1 = (t < L1);
        gatefn(t00, z00, m0, c00, h00);
        gatefn(t01, z01, m0, c01, h01);
        gatefn(t10, z10, m1, c10, h10);
        gatefn(t11, z11, m1, c11, h11);

        // tagged publish DIRECT from registers (earliest possible issue).
        // Partner unit (u0^1) lives in lane c16^4 (k4 parity neighbor).
        if (ts < TT - 1) {
            unsigned long long* const dst = Hwd + (size_t)((ts + 1) & 1) * WBUF;
            const unsigned long long tg =
                ((unsigned long long)(uint32_t)(ts + 1)) << 32;
            float p00 = __shfl_xor(h00, 4);
            float p10 = __shfl_xor(h10, 4);
            float p01 = __shfl_xor(h01, 4);
            float p11 = __shfl_xor(h11, 4);
            if ((k4 & 1) == 0) {
                const int gw0 = 15 * blk + 4 * wv + (k4 >> 1);
                uint32_t q00 = (uint32_t)f2bf(h00) | ((uint32_t)f2bf(p00) << 16);
                uint32_t q10 = (uint32_t)f2bf(h10) | ((uint32_t)f2bf(p10) << 16);
                __hip_atomic_store(&dst[b0 * WPR + gw0], tg | q00,
                                   __ATOMIC_RELAXED, __HIP_MEMORY_SCOPE_AGENT);
                __hip_atomic_store(&dst[(b0 + 16) * WPR + gw0], tg | q10,
                                   __ATOMIC_RELAXED, __HIP_MEMORY_SCOPE_AGENT);
                if (v1) {
                    uint32_t q01 = (uint32_t)f2bf(h01) | ((uint32_t)f2bf(p01) << 16);
                    uint32_t q11 = (uint32_t)f2bf(h11) | ((uint32_t)f2bf(p11) << 16);
                    __hip_atomic_store(&dst[b0 * WPR + gw0 + 2], tg | q01,
                                       __ATOMIC_RELAXED, __HIP_MEMORY_SCOPE_AGENT);
                    __hip_atomic_store(&dst[(b0 + 16) * WPR + gw0 + 2], tg | q11,
                                       __ATOMIC_RELAXED, __HIP_MEMORY_SCOPE_AGENT);
                }
            }
        }

        // hstage + coalesced private hout (off the critical path)
        hstage[b0 * UPB + u0]        = f2bf(h00);
        hstage[(b0 + 16) * UPB + u0] = f2bf(h10);
        if (v1) {
            hstage[b0 * UPB + u0 + 4]        = f2bf(h01);
            hstage[(b0 + 16) * UPB + u0 + 4] = f2bf(h11);
        }
        __syncthreads();                                  // (2)

        for (int i = tid; i < BB * (UPB / 2); i += 256) {
            int b = i / (UPB / 2), k = i - b * (UPB / 2);
            uint32_t val = (uint32_t)hstage[b * UPB + 2 * k] |
                           ((uint32_t)hstage[b * UPB + 2 * k + 1] << 16);
            *(uint32_t*)&hout[((size_t)(b * TT + t)) * UU + UPB * blk + 2 * k] = val;
        }
    }
}

// ---------------------------------------------------------------------------
// Kernel 4: out[r] = [hf[r] ; hb[r]] @ fc_W + fc_b.
// ---------------------------------------------------------------------------
__global__ __launch_bounds__(256) void fc_out(
    const bf16_t* __restrict__ hf, const bf16_t* __restrict__ hb,
    const void* __restrict__ fcW, const void* __restrict__ fcb,
    void* __restrict__ out, const int* __restrict__ flagp) {

    const int f32m = *flagp;
    __shared__ float W[2 * UU * NTOK];
    __shared__ float bias[NTOK];
    const int tid = threadIdx.x;
    for (int i = tid; i < 2 * UU * NTOK; i += 256) W[i] = ldf(fcW, i, f32m);
    if (tid < NTOK) bias[tid] = ldf(fcb, tid, f32m);
    __syncthreads();

    const int r = blockIdx.x * 256 + tid;
    const bf16_t* hfr = hf + (size_t)r * UU;
    const bf16_t* hbr = hb + (size_t)r * UU;
    float s0 = bias[0], s1 = bias[1], s2 = bias[2];
    for (int u = 0; u < UU; u++) {
        float f = bf2f(hfr[u]);
        s0 += f * W[u * 3 + 0];
        s1 += f * W[u * 3 + 1];
        s2 += f * W[u * 3 + 2];
    }
    for (int u = 0; u < UU; u++) {
        float f = bf2f(hbr[u]);
        s0 += f * W[(UU + u) * 3 + 0];
        s1 += f * W[(UU + u) * 3 + 1];
        s2 += f * W[(UU + u) * 3 + 2];
    }
    if (f32m) {
        float* o = (float*)out;
        o[(size_t)r * 3 + 0] = s0;
        o[(size_t)r * 3 + 1] = s1;
        o[(size_t)r * 3 + 2] = s2;
    } else {
        bf16_t* o = (bf16_t*)out;
        o[(size_t)r * 3 + 0] = f2bf(s0);
        o[(size_t)r * 3 + 1] = f2bf(s1);
        o[(size_t)r * 3 + 2] = f2bf(s2);
    }
}

// ---------------------------------------------------------------------------
extern "C" void kernel_launch(void* const* d_in, const int* in_sizes, int n_in,
                              void* d_out, int out_size, void* d_ws, size_t ws_size,
                              hipStream_t stream) {
    const int* inputs = (const int*)d_in[0];
    const int* seqlen = (const int*)d_in[1];
    const void* emb  = d_in[2];
    const void* Wk_f = d_in[3];
    const void* Wr_f = d_in[4];
    const void* b_f  = d_in[5];
    const void* Wk_b = d_in[6];
    const void* Wr_b = d_in[7];
    const void* b_b  = d_in[8];
    const void* fcW  = d_in[9];
    const void* fcb  = d_in[10];

    // workspace layout (bytes)
    char* ws = (char*)d_ws;
    int*    flag   = (int*)(ws + 0);                           // 64 B
    unsigned long long* Hw = (unsigned long long*)(ws + 64);   // 153,600
    bf16_t* WrPT_f = (bf16_t*)(ws + 153664);         // 729,600
    bf16_t* WrPT_b = (bf16_t*)(ws + 883264);         // 729,600
    bf16_t* zxPf   = (bf16_t*)(ws + 1612864);        // 39,321,600
    bf16_t* zxPb   = (bf16_t*)(ws + 40934464);       // 39,321,600
    bf16_t* hfbuf  = (bf16_t*)(ws + 80256064);       // 9,830,400
    bf16_t* hbbuf  = (bf16_t*)(ws + 90086464);       // 9,830,400 -> 99,916,864
    // WkT/biasP alias hfbuf: consumed by zx_gemm3 (before rec), clobbered by rec
    bf16_t* WkT    = hfbuf;                          // 2*1280*320*2 = 1,638,400
    bf16_t* biasP  = hfbuf + 2 * WKROWS * WKSTR;     // 5,120

    detect_dtype<<<1, 256, 0, stream>>>((const uint16_t*)emb, flag);
    {
        dim3 grid((G4 * HROW + 255) / 256, 2);
        prep_wrp<<<grid, 256, 0, stream>>>(Wr_f, Wr_b, WrPT_f, WrPT_b, flag);
    }
    {
        dim3 grid((WKROWS * WKSTR + 255) / 256, 2);
        prep_wkt<<<grid, 256, 0, stream>>>(Wk_f, b_f, Wk_b, b_b, WkT, biasP, flag);
    }
    init_state<<<75, 256, 0, stream>>>(Hw);
    {
        dim3 grid(256, 2);
        zx_gemm3<<<grid, 256, 0, stream>>>(inputs, emb, WkT, biasP,
                                           zxPf, zxPb, flag);
    }
    lstm_rec8<<<2 * KB, 256, 0, stream>>>(zxPf, zxPb, WrPT_f, WrPT_b, seqlen,
                                          Hw, hfbuf, hbbuf);
    fc_out<<<(BB * TT) / 256, 256, 0, stream>>>(hfbuf, hbbuf, fcW, fcb,
                                                d_out, flag);
}

// Round 11
// 1786.225 us; speedup vs baseline: 1.0680x; 1.0680x over previous
//
#include <hip/hip_runtime.h>
#include <stdint.h>

// Bidirectional LSTM.  B=32, T=512, V=32000, D=300, U=300, NT=3.
// R24 = R22 base + (a) register-direct publish (R23's refcheck'd shfl_xor
// pair-pack) inside the FLAG protocol, issued right after gates; barrier(2)
// doubles as the drain (syncthreads = vmcnt(0)); barrier(3) deleted; flag
// stored right after barrier(2).  (b) fc_out bf16 loads vectorized (uint2).
// R23 post-mortem: tagged-word poll re-iterates (FETCH 135->212MB) because
// readiness isn't batched; flag protocol's one-word-per-producer poll is
// single-iteration.  Tagged payload refuted twice (R14, R23).
// History: R13=2065/rec1751, R19=1823/rec1509, R21=1723/rec1509,
// R22=1719/rec1501 (revert target), R23=1908/rec1710 (reverted).

#define BB 32
#define TT 512
#define DD 300
#define UU 300
#define G4 1200   // 4*U
#define NTOK 3

#define KB   10    // rec blocks per direction
#define UPB  30    // units per rec block
#define NCOL 120   // gate-cols per rec block (4*UPB)
#define KTILES 10  // K = 320 (300 padded), 10 tiles of 32
#define HSTR 320   // swizzled LDS row stride (elems)
#define HROW 304   // global H row stride (elems)

#define WKROWS 1280  // WkT padded p-rows
#define WKSTR  320   // WkT padded k-stride

typedef uint16_t bf16_t;
typedef short  s16x8 __attribute__((ext_vector_type(8)));
typedef float  f32x4 __attribute__((ext_vector_type(4)));

union U8 { unsigned long long q[2]; s16x8 v; };

__device__ __forceinline__ float bf2f(uint16_t u) {
    union { uint32_t i; float f; } v; v.i = ((uint32_t)u) << 16; return v.f;
}
__device__ __forceinline__ uint16_t f2bf(float f) {
    union { uint32_t i; float f; } v; v.f = f;
    uint32_t r = v.i + 0x7fffu + ((v.i >> 16) & 1u);   // RNE
    return (uint16_t)(r >> 16);
}
__device__ __forceinline__ float ldf(const void* base, size_t idx, int f32m) {
    return f32m ? ((const float*)base)[idx]
                : bf2f(((const uint16_t*)base)[idx]);
}

// 4x4 transpose across lane bits 0..1 (verified R7)
__device__ __forceinline__ f32x4 xpose4(f32x4 v, int lane) {
    f32x4 t, w, s, r;
    t[0] = __shfl_xor(v[0], 1); t[1] = __shfl_xor(v[1], 1);
    t[2] = __shfl_xor(v[2], 1); t[3] = __shfl_xor(v[3], 1);
    if ((lane & 1) == 0) { w[0]=v[0]; w[1]=t[0]; w[2]=v[2]; w[3]=t[2]; }
    else                 { w[0]=t[1]; w[1]=v[1]; w[2]=t[3]; w[3]=v[3]; }
    s[0] = __shfl_xor(w[0], 2); s[1] = __shfl_xor(w[1], 2);
    s[2] = __shfl_xor(w[2], 2); s[3] = __shfl_xor(w[3], 2);
    if ((lane & 2) == 0) { r[0]=w[0]; r[1]=w[1]; r[2]=s[0]; r[3]=s[1]; }
    else                 { r[0]=s[2]; r[1]=s[3]; r[2]=w[2]; r[3]=w[3]; }
    return r;
}

// fast sigmoid/tanh: v_exp + v_rcp (rel err ~1e-6, margin 6x vs threshold)
__device__ __forceinline__ float fsig(float x) {
    return __builtin_amdgcn_rcpf(1.f + __expf(-x));
}
__device__ __forceinline__ float ftanh(float x) {
    float cx = fminf(10.f, fmaxf(-10.f, x));
    float e = __expf(2.f * cx);
    return (e - 1.f) * __builtin_amdgcn_rcpf(e + 1.f);
}

__device__ __forceinline__ void gatefn(f32x4 zv, uint2 zp, bool m,
                                       float& c, float& h) {
    float zi = zv[0] + bf2f((uint16_t)(zp.x & 0xffff));
    float zf = zv[1] + bf2f((uint16_t)(zp.x >> 16));
    float zg = zv[2] + bf2f((uint16_t)(zp.y & 0xffff));
    float zo = zv[3] + bf2f((uint16_t)(zp.y >> 16));
    float si = fsig(zi);
    float sf = fsig(zf);
    float so = fsig(zo);
    float tg = ftanh(zg);
    float cn = sf * c + si * tg;
    float hn = so * ftanh(cn);
    if (m) { c = cn; h = hn; }
}

// ---------------------------------------------------------------------------
// Kernel 0: dtype detector (f32 vs bf16 inputs).
// ---------------------------------------------------------------------------
__global__ void detect_dtype(const uint16_t* __restrict__ emb_u16,
                             int* __restrict__ flag) {
    __shared__ float red[256];
    const int tid = threadIdx.x;
    float m = 0.f;
    for (int k = tid; k < 4096; k += 256)
        m = fmaxf(m, fabsf(bf2f(emb_u16[2 * k])));
    red[tid] = m;
    __syncthreads();
    for (int s = 128; s > 0; s >>= 1) {
        if (tid < s) red[tid] = fmaxf(red[tid], red[tid + s]);
        __syncthreads();
    }
    if (tid == 0) flag[0] = (red[0] > 1.0e3f) ? 1 : 0;
}

// ---------------------------------------------------------------------------
// Kernel 1: build WrPT[dir][p][k] (rec weights): p = 4u+g, k-major rows of
// length 304 (k>=300 zero).  WrPT[p][k] = Wr[k][g*300+u].
// ---------------------------------------------------------------------------
__global__ void prep_wrp(const void* __restrict__ Wr_f,
                         const void* __restrict__ Wr_b,
                         bf16_t* __restrict__ WrPT_f,
                         bf16_t* __restrict__ WrPT_b,
                         const int* __restrict__ flagp) {
    const int f32m = *flagp;
    int idx = blockIdx.x * 256 + threadIdx.x;          // over 1200*304
    const void* src = blockIdx.y ? Wr_b : Wr_f;
    bf16_t*     dst = blockIdx.y ? WrPT_b : WrPT_f;
    if (idx < G4 * HROW) {
        int p = idx / HROW;
        int k = idx - p * HROW;
        int u = p >> 2, g = p & 3;
        float v = (k < DD) ? ldf(src, (size_t)k * G4 + g * UU + u, f32m) : 0.f;
        dst[idx] = f2bf(v);
    }
}

// ---------------------------------------------------------------------------
// Kernel 1c: build WkT[dir][p][k] (zx weights, permuted+padded) + biasP.
// ---------------------------------------------------------------------------
__global__ void prep_wkt(const void* __restrict__ Wk_f, const void* __restrict__ b_f,
                         const void* __restrict__ Wk_b, const void* __restrict__ b_b,
                         bf16_t* __restrict__ WkT, bf16_t* __restrict__ biasP,
                         const int* __restrict__ flagp) {
    const int f32m = *flagp;
    const int dir = blockIdx.y;
    const void* Wk = dir ? Wk_b : Wk_f;
    const void* bs = dir ? b_b  : b_f;
    bf16_t* dst = WkT + (size_t)dir * (WKROWS * WKSTR);
    int idx = blockIdx.x * 256 + threadIdx.x;          // over 1280*320
    if (idx < WKROWS * WKSTR) {
        int p = idx / WKSTR;
        int k = idx - p * WKSTR;
        int u = p >> 2, g = p & 3;
        float v = (p < G4 && k < DD) ? ldf(Wk, (size_t)k * G4 + g * UU + u, f32m)
                                     : 0.f;
        dst[idx] = f2bf(v);
        if (idx < WKROWS) {
            int pp = idx, uu = pp >> 2, gg = pp & 3;
            biasP[dir * WKROWS + idx] =
                (pp < G4) ? f2bf(ldf(bs, gg * UU + uu, f32m)) : (bf16_t)0;
        }
    }
}

// ---------------------------------------------------------------------------
// Kernel 1b: zero H double-buffers and ready flags.
// ---------------------------------------------------------------------------
__global__ void init_state(bf16_t* __restrict__ Hglob, int* __restrict__ flags) {
    int i = blockIdx.x * 256 + threadIdx.x;
    if (i < 2 * 2 * BB * HROW) Hglob[i] = 0;
    if (i < 2 * TT * 16) flags[i] = 0;
}

// ---------------------------------------------------------------------------
// Kernel 2: MFMA zx GEMM, A staged ONCE (R21-verbatim).
// ---------------------------------------------------------------------------
#define ZM 64
#define ZN 128
__global__ __launch_bounds__(256, 2) void zx_gemm3(
    const int* __restrict__ inputs, const void* __restrict__ emb,
    const bf16_t* __restrict__ WkTall, const bf16_t* __restrict__ biasP,
    bf16_t* __restrict__ zxf, bf16_t* __restrict__ zxb,
    const int* __restrict__ flagp) {

    const int f32m = *flagp;
    const int dir = blockIdx.y;
    const bf16_t* WkT = WkTall + (size_t)dir * (WKROWS * WKSTR);
    const bf16_t* bp  = biasP + dir * WKROWS;
    bf16_t* out = dir ? zxb : zxf;

    const int tid = threadIdx.x;
    const int rowBase = blockIdx.x * ZM;

    __shared__ __align__(16) uint16_t Alds[ZM * HSTR];   // 40,960 B
    __shared__ int rowids[ZM];

    if (tid < ZM) rowids[tid] = inputs[rowBase + tid];
    for (int i = tid; i < ZM * HSTR; i += 256) Alds[i] = 0;
    __syncthreads();

    // stage A gathered ONCE: 64 rows x 38 groups of 8, swizzled
    for (int i = tid; i < ZM * 38; i += 256) {
        int r = i / 38, g = i - 38 * r;
        int k0 = g * 8;
        const size_t eb = (size_t)rowids[r] * DD + k0;
        uint16_t tmp[8];
        if (g < 37) {
            if (f32m) {
                const float* ef = (const float*)emb + eb;
#pragma unroll
                for (int e = 0; e < 8; e++) tmp[e] = f2bf(ef[e]);
            } else {
                *(uint4*)tmp = *(const uint4*)((const uint16_t*)emb + eb);
            }
        } else {
#pragma unroll
            for (int e = 0; e < 8; e++) {
                int k = k0 + e;
                tmp[e] = (k < DD)
                    ? (f32m ? f2bf(((const float*)emb)[(size_t)rowids[r] * DD + k])
                            : ((const uint16_t*)emb)[(size_t)rowids[r] * DD + k])
                    : (uint16_t)0;
            }
        }
        *(uint4*)&Alds[r * HSTR + ((g ^ (r & 7)) << 3)] = *(uint4*)tmp;
    }
    __syncthreads();

    const int lane = tid & 63;
    const int wv   = tid >> 6;
    const int q    = lane >> 4;
    const int c16  = lane & 15;
    const int n0   = 32 * wv;
    const int sw7  = c16 & 7;
    const bool evn = ((lane & 1) == 0);

    for (int nt = 0; nt < 10; nt++) {
        const int pb = nt * ZN;
        const int p0 = pb + n0 + c16;
        const int p1 = p0 + 16;
        const float bv0 = bf2f(bp[p0]);
        const float bv1 = bf2f(bp[p1]);

        f32x4 acc[4][2];
#pragma unroll
        for (int mt = 0; mt < 4; mt++)
            for (int nh = 0; nh < 2; nh++) acc[mt][nh] = (f32x4){0.f,0.f,0.f,0.f};

#pragma unroll
        for (int kt = 0; kt < KTILES; kt++) {
            int k0 = 32 * kt + 8 * q;
            int sw = (((kt * 4 + q) ^ sw7) << 3);
            s16x8 b0 = *(const s16x8*)&WkT[(size_t)p0 * WKSTR + k0];
            s16x8 b1 = *(const s16x8*)&WkT[(size_t)p1 * WKSTR + k0];
#pragma unroll
            for (int mt = 0; mt < 4; mt++) {
                s16x8 af = *(const s16x8*)&Alds[(16 * mt + c16) * HSTR + sw];
                acc[mt][0] = __builtin_amdgcn_mfma_f32_16x16x32_bf16(af, b0, acc[mt][0], 0, 0, 0);
                acc[mt][1] = __builtin_amdgcn_mfma_f32_16x16x32_bf16(af, b1, acc[mt][1], 0, 0, 0);
            }
        }

        // epilogue: bias add, bf16, pair-pack via shfl_xor(1), even-lane u32
#pragma unroll
        for (int mt = 0; mt < 4; mt++) {
#pragma unroll
            for (int nh = 0; nh < 2; nh++) {
                const int p = (nh == 0) ? p0 : p1;
                const float bv = (nh == 0) ? bv0 : bv1;
#pragma unroll
                for (int r = 0; r < 4; r++) {
                    uint32_t mine = f2bf(acc[mt][nh][r] + bv);
                    uint32_t other = (uint32_t)__shfl_xor((int)mine, 1);
                    if (evn && p < G4) {
                        uint32_t pk = mine | (other << 16);
                        int row = rowBase + 16 * mt + 4 * q + r;
                        *(uint32_t*)&out[(size_t)row * G4 + p] = pk;
                    }
                }
            }
        }
    }
}

// ---------------------------------------------------------------------------
// Kernel 3: hybrid MFMA recurrence.  20 blocks, 256 thr.  R24 structure:
// fused speculative poll (R22) -> scatter -> barrier(1) -> MFMA -> gates ->
// register-direct publish (issue early) -> hstage -> barrier(2)=drain ->
// flag store -> coalesced hout.  2 barriers/step.
// ---------------------------------------------------------------------------
__global__ __launch_bounds__(256, 1) void lstm_rec9(
    const bf16_t* __restrict__ zxf, const bf16_t* __restrict__ zxb,
    const bf16_t* __restrict__ WrPT_f, const bf16_t* __restrict__ WrPT_b,
    const int* __restrict__ seqlen,
    bf16_t* __restrict__ Hglob, int* __restrict__ flags,
    bf16_t* __restrict__ hf, bf16_t* __restrict__ hb) {

    const int blk = blockIdx.x % KB;
    const int dir = blockIdx.x / KB;
    const bf16_t* zx   = dir ? zxb    : zxf;
    const bf16_t* WrPT = dir ? WrPT_b : WrPT_f;
    bf16_t*       hout = dir ? hb : hf;
    bf16_t*       Hg   = Hglob + (size_t)dir * (2 * BB * HROW);
    int*          fbase = flags + dir * (TT * 16);

    __shared__ __align__(16) uint16_t Hlds[BB * HSTR];    // 20,480 B
    __shared__ uint16_t hstage[BB * UPB];                 //  1,920 B

    const int tid  = threadIdx.x;
    const int lane = tid & 63;
    const int wv   = tid >> 6;
    const int q    = lane >> 4;
    const int c16  = lane & 15;
    const int n0   = 32 * wv;
    const int sw7  = c16 & 7;
    const int k4   = c16 >> 2;
    const int j4   = c16 & 3;
    const int u0   = 8 * wv + k4;
    const int b0   = 4 * q + j4;
    const bool v1  = (u0 + 4 < UPB);
    const bool pollme = (lane < KB) && (lane != blk);

    // one-time: zero Hlds (pad groups 38,39 must read 0), B-frags to regs
    for (int i = tid; i < BB * HSTR; i += 256) Hlds[i] = 0;
    U8 Bf0[KTILES], Bf1[KTILES];
#pragma unroll
    for (int kt = 0; kt < KTILES; kt++) {
        int k0 = 32 * kt + 8 * q;
        int col0 = n0 + c16, col1 = n0 + 16 + c16;
        U8 z; z.q[0] = 0; z.q[1] = 0;
        Bf0[kt] = z; Bf1[kt] = z;
        if (k0 < 304) {
            if (col0 < NCOL)
                Bf0[kt].v = *(const s16x8*)&WrPT[(size_t)(NCOL * blk + col0) * HROW + k0];
            if (col1 < NCOL)
                Bf1[kt].v = *(const s16x8*)&WrPT[(size_t)(NCOL * blk + col1) * HROW + k0];
        }
    }
    float c00 = 0.f, c01 = 0.f, c10 = 0.f, c11 = 0.f;
    float h00 = 0.f, h01 = 0.f, h10 = 0.f, h11 = 0.f;
    const int L0 = seqlen[b0];
    const int L1 = seqlen[b0 + 16];
    __syncthreads();

    for (int ts = 0; ts < TT; ts++) {
        const int t = dir ? (TT - 1 - ts) : ts;

        // zx prefetch (overlaps the flag wait)
        const size_t zr0 = ((size_t)(b0 * TT + t)) * G4 + NCOL * blk;
        const size_t zr1 = ((size_t)((b0 + 16) * TT + t)) * G4 + NCOL * blk;
        uint2 z00 = *(const uint2*)&zx[zr0 + 4 * u0];
        uint2 z10 = *(const uint2*)&zx[zr1 + 4 * u0];
        uint2 z01 = {0, 0}, z11 = {0, 0};
        if (v1) {
            z01 = *(const uint2*)&zx[zr0 + 4 * (u0 + 4)];
            z11 = *(const uint2*)&zx[zr1 + 4 * (u0 + 4)];
        }

        // fused poll + speculative H reload (R22-verified):
        // flag sample issued FIRST, H loads issued right behind it; if the
        // sample shows all-set, the H loads are valid (payload acks drained
        // before the flag store departed the producer).
        const unsigned long long* Hsrc64 =
            (const unsigned long long*)(Hg + (size_t)(ts & 1) * (BB * HROW));
        unsigned long long hv[10];
        if (ts > 0) {
            int* fl = fbase + (ts - 1) * 16;
            for (;;) {
                int a = pollme ? __hip_atomic_load(&fl[lane], __ATOMIC_RELAXED,
                                                   __HIP_MEMORY_SCOPE_AGENT) : 1;
                asm volatile("" ::: "memory");          // pin flag->H issue order (IR)
                __builtin_amdgcn_sched_barrier(0);      // pin at MIR level too
#pragma unroll
                for (int k = 0; k < 9; k++)
                    hv[k] = __hip_atomic_load(&Hsrc64[tid + 256 * k],
                                              __ATOMIC_RELAXED,
                                              __HIP_MEMORY_SCOPE_AGENT);
                if (tid < 128)
                    hv[9] = __hip_atomic_load(&Hsrc64[2304 + tid],
                                              __ATOMIC_RELAXED,
                                              __HIP_MEMORY_SCOPE_AGENT);
                if (__all(a != 0)) break;
            }
        } else {
#pragma unroll
            for (int k = 0; k < 9; k++)
                hv[k] = __hip_atomic_load(&Hsrc64[tid + 256 * k],
                                          __ATOMIC_RELAXED,
                                          __HIP_MEMORY_SCOPE_AGENT);
            if (tid < 128)
                hv[9] = __hip_atomic_load(&Hsrc64[2304 + tid],
                                          __ATOMIC_RELAXED,
                                          __HIP_MEMORY_SCOPE_AGENT);
        }
#pragma unroll
        for (int k = 0; k < 9; k++) {
            int i = tid + 256 * k;
            int b = i / 76, x = i - 76 * b;
            *(unsigned long long*)
                &Hlds[b * HSTR + ((((x >> 1) ^ (b & 7)) << 3) | ((x & 1) << 2))]
                = hv[k];
        }
        if (tid < 128) {
            int i = 2304 + tid;
            int b = i / 76, x = i - 76 * b;
            *(unsigned long long*)
                &Hlds[b * HSTR + ((((x >> 1) ^ (b & 7)) << 3) | ((x & 1) << 2))]
                = hv[9];
        }
        __syncthreads();                                  // (1)

        // MFMA: A from Hlds (swizzled), B from registers
        f32x4 acc00 = {0.f,0.f,0.f,0.f}, acc01 = {0.f,0.f,0.f,0.f};
        f32x4 acc10 = {0.f,0.f,0.f,0.f}, acc11 = {0.f,0.f,0.f,0.f};
#pragma unroll
        for (int kt = 0; kt < KTILES; kt++) {
            int sw = (((kt * 4 + q) ^ sw7) << 3);
            s16x8 a0 = *(const s16x8*)&Hlds[c16 * HSTR + sw];
            s16x8 a1 = *(const s16x8*)&Hlds[(c16 + 16) * HSTR + sw];
            acc00 = __builtin_amdgcn_mfma_f32_16x16x32_bf16(a0, Bf0[kt].v, acc00, 0, 0, 0);
            acc01 = __builtin_amdgcn_mfma_f32_16x16x32_bf16(a0, Bf1[kt].v, acc01, 0, 0, 0);
            acc10 = __builtin_amdgcn_mfma_f32_16x16x32_bf16(a1, Bf0[kt].v, acc10, 0, 0, 0);
            acc11 = __builtin_amdgcn_mfma_f32_16x16x32_bf16(a1, Bf1[kt].v, acc11, 0, 0, 0);
        }

        // transpose + gates in registers (R7-verified mapping)
        f32x4 t00 = xpose4(acc00, lane);
        f32x4 t01 = xpose4(acc01, lane);
        f32x4 t10 = xpose4(acc10, lane);
        f32x4 t11 = xpose4(acc11, lane);
        const bool m0 = (t < L0);
        const bool m1 = (t < L1);
        gatefn(t00, z00, m0, c00, h00);
        gatefn(t01, z01, m0, c01, h01);
        gatefn(t10, z10, m1, c10, h10);
        gatefn(t11, z11, m1, c11, h11);

        // register-direct publish (R23-refcheck'd pair mapping), issued as
        // early as possible; barrier(2) below doubles as the drain.
        // Partner unit (u0^1) lives in lane c16^4 (k4-parity neighbor).
        if (ts < TT - 1) {
            bf16_t* Hdst = Hg + (size_t)((ts + 1) & 1) * (BB * HROW);
            float p00 = __shfl_xor(h00, 4);
            float p10 = __shfl_xor(h10, 4);
            float p01 = __shfl_xor(h01, 4);
            float p11 = __shfl_xor(h11, 4);
            if ((k4 & 1) == 0) {
                const int w0 = 4 * wv + (k4 >> 1);       // word idx in [0,15)
                uint32_t q00 = (uint32_t)f2bf(h00) | ((uint32_t)f2bf(p00) << 16);
                uint32_t q10 = (uint32_t)f2bf(h10) | ((uint32_t)f2bf(p10) << 16);
                __hip_atomic_store(
                    (uint32_t*)&Hdst[b0 * HROW + UPB * blk + 2 * w0], q00,
                    __ATOMIC_RELAXED, __HIP_MEMORY_SCOPE_AGENT);
                __hip_atomic_store(
                    (uint32_t*)&Hdst[(b0 + 16) * HROW + UPB * blk + 2 * w0], q10,
                    __ATOMIC_RELAXED, __HIP_MEMORY_SCOPE_AGENT);
                if (v1) {
                    uint32_t q01 = (uint32_t)f2bf(h01) | ((uint32_t)f2bf(p01) << 16);
                    uint32_t q11 = (uint32_t)f2bf(h11) | ((uint32_t)f2bf(p11) << 16);
                    __hip_atomic_store(
                        (uint32_t*)&Hdst[b0 * HROW + UPB * blk + 2 * (w0 + 2)], q01,
                        __ATOMIC_RELAXED, __HIP_MEMORY_SCOPE_AGENT);
                    __hip_atomic_store(
                        (uint32_t*)&Hdst[(b0 + 16) * HROW + UPB * blk + 2 * (w0 + 2)], q11,
                        __ATOMIC_RELAXED, __HIP_MEMORY_SCOPE_AGENT);
                }
            }
        }

        // hstage for coalesced hout
        hstage[b0 * UPB + u0]        = f2bf(h00);
        hstage[(b0 + 16) * UPB + u0] = f2bf(h10);
        if (v1) {
            hstage[b0 * UPB + u0 + 4]        = f2bf(h01);
            hstage[(b0 + 16) * UPB + u0 + 4] = f2bf(h11);
        }
        __syncthreads();                                  // (2) = drain

        if (ts < TT - 1 && tid == 0)
            __hip_atomic_store(&fbase[ts * 16 + blk], 1, __ATOMIC_RELAXED,
                               __HIP_MEMORY_SCOPE_AGENT);

        // private hout stores, off the critical path (coalesced from hstage)
        for (int i = tid; i < BB * (UPB / 2); i += 256) {
            int b = i / (UPB / 2), k = i - b * (UPB / 2);
            uint32_t val = (uint32_t)hstage[b * UPB + 2 * k] |
                           ((uint32_t)hstage[b * UPB + 2 * k + 1] << 16);
            *(uint32_t*)&hout[((size_t)(b * TT + t)) * UU + UPB * blk + 2 * k] = val;
        }
    }
}

// ---------------------------------------------------------------------------
// Kernel 4: out[r] = [hf[r] ; hb[r]] @ fc_W + fc_b.  (vectorized h loads)
// ---------------------------------------------------------------------------
__global__ __launch_bounds__(256) void fc_out(
    const bf16_t* __restrict__ hf, const bf16_t* __restrict__ hb,
    const void* __restrict__ fcW, const void* __restrict__ fcb,
    void* __restrict__ out, const int* __restrict__ flagp) {

    const int f32m = *flagp;
    __shared__ float W[2 * UU * NTOK];
    __shared__ float bias[NTOK];
    const int tid = threadIdx.x;
    for (int i = tid; i < 2 * UU * NTOK; i += 256) W[i] = ldf(fcW, i, f32m);
    if (tid < NTOK) bias[tid] = ldf(fcb, tid, f32m);
    __syncthreads();

    const int r = blockIdx.x * 256 + tid;
    const bf16_t* hfr = hf + (size_t)r * UU;
    const bf16_t* hbr = hb + (size_t)r * UU;
    float s0 = bias[0], s1 = bias[1], s2 = bias[2];
#pragma unroll 5
    for (int g = 0; g < UU / 4; g++) {          // 75 uint2 loads (4 bf16 each)
        uint2 v = *(const uint2*)&hfr[g * 4];
        const float* Wp = &W[g * 12];
#pragma unroll
        for (int e = 0; e < 4; e++) {
            uint32_t w = (e < 2) ? v.x : v.y;
            float f = bf2f((uint16_t)((e & 1) ? (w >> 16) : (w & 0xffff)));
            s0 += f * Wp[e * 3 + 0];
            s1 += f * Wp[e * 3 + 1];
            s2 += f * Wp[e * 3 + 2];
        }
    }
#pragma unroll 5
    for (int g = 0; g < UU / 4; g++) {
        uint2 v = *(const uint2*)&hbr[g * 4];
        const float* Wp = &W[(UU + g * 4) * 3];
#pragma unroll
        for (int e = 0; e < 4; e++) {
            uint32_t w = (e < 2) ? v.x : v.y;
            float f = bf2f((uint16_t)((e & 1) ? (w >> 16) : (w & 0xffff)));
            s0 += f * Wp[e * 3 + 0];
            s1 += f * Wp[e * 3 + 1];
            s2 += f * Wp[e * 3 + 2];
        }
    }
    if (f32m) {
        float* o = (float*)out;
        o[(size_t)r * 3 + 0] = s0;
        o[(size_t)r * 3 + 1] = s1;
        o[(size_t)r * 3 + 2] = s2;
    } else {
        bf16_t* o = (bf16_t*)out;
        o[(size_t)r * 3 + 0] = f2bf(s0);
        o[(size_t)r * 3 + 1] = f2bf(s1);
        o[(size_t)r * 3 + 2] = f2bf(s2);
    }
}

// ---------------------------------------------------------------------------
extern "C" void kernel_launch(void* const* d_in, const int* in_sizes, int n_in,
                              void* d_out, int out_size, void* d_ws, size_t ws_size,
                              hipStream_t stream) {
    const int* inputs = (const int*)d_in[0];
    const int* seqlen = (const int*)d_in[1];
    const void* emb  = d_in[2];
    const void* Wk_f = d_in[3];
    const void* Wr_f = d_in[4];
    const void* b_f  = d_in[5];
    const void* Wk_b = d_in[6];
    const void* Wr_b = d_in[7];
    const void* b_b  = d_in[8];
    const void* fcW  = d_in[9];
    const void* fcb  = d_in[10];

    // workspace layout (bytes)
    char* ws = (char*)d_ws;
    int*    flag   = (int*)(ws + 0);                 // 64 B
    int*    flags  = (int*)(ws + 64);                // 65,536
    bf16_t* Hglob  = (bf16_t*)(ws + 65664);          // 77,824
    bf16_t* WrPT_f = (bf16_t*)(ws + 143488);         // 729,600
    bf16_t* WrPT_b = (bf16_t*)(ws + 873088);         // 729,600
    bf16_t* zxPf   = (bf16_t*)(ws + 1602688);        // 39,321,600
    bf16_t* zxPb   = (bf16_t*)(ws + 40924288);       // 39,321,600
    bf16_t* hfbuf  = (bf16_t*)(ws + 80245888);       // 9,830,400
    bf16_t* hbbuf  = (bf16_t*)(ws + 90076288);       // 9,830,400 -> 99,906,688
    // WkT/biasP alias hfbuf: consumed by zx_gemm3 (before rec), clobbered by rec
    bf16_t* WkT    = hfbuf;                          // 2*1280*320*2 = 1,638,400
    bf16_t* biasP  = hfbuf + 2 * WKROWS * WKSTR;     // 5,120

    detect_dtype<<<1, 256, 0, stream>>>((const uint16_t*)emb, flag);
    {
        dim3 grid((G4 * HROW + 255) / 256, 2);
        prep_wrp<<<grid, 256, 0, stream>>>(Wr_f, Wr_b, WrPT_f, WrPT_b, flag);
    }
    {
        dim3 grid((WKROWS * WKSTR + 255) / 256, 2);
        prep_wkt<<<grid, 256, 0, stream>>>(Wk_f, b_f, Wk_b, b_b, WkT, biasP, flag);
    }
    init_state<<<64, 256, 0, stream>>>(Hglob, flags);
    {
        dim3 grid(256, 2);
        zx_gemm3<<<grid, 256, 0, stream>>>(inputs, emb, WkT, biasP,
                                           zxPf, zxPb, flag);
    }
    lstm_rec9<<<2 * KB, 256, 0, stream>>>(zxPf, zxPb, WrPT_f, WrPT_b, seqlen,
                                          Hglob, flags, hfbuf, hbbuf);
    fc_out<<<(BB * TT) / 256, 256, 0, stream>>>(hfbuf, hbbuf, fcW, fcb,
                                                d_out, flag);
}

// Round 12
// 1708.412 us; speedup vs baseline: 1.1166x; 1.0455x over previous
//
#include <hip/hip_runtime.h>
#include <stdint.h>

// Bidirectional LSTM.  B=32, T=512, V=32000, D=300, U=300, NT=3.
// R25 = BANK THE BEST: rec kernel reverted to R22-verbatim (verified rec
// 1501us); fc_out keeps R24's uint2-vectorized h loads (refcheck'd, ~-20us).
// R24 post-mortem: register-direct publish scatters u32 stores across 16 H
// rows per wave (WRITE 58->119MB, partial-line writebacks) -> rec +88us.
// Exchange protocol now probed from all sides: consumer detect (R19 win),
// consumer load latency (R22 neutral: already hidden), producer drain/flag
// (R20/R23/R24 regress), transport scope (R15-R17 fail).  R22's structure is
// the measured ~2RT/step protocol floor for this forced 20-CU L3 all-to-all.
// History: R13=2065/rec1751, R19=1823/rec1509, R21=1723/rec1509,
// R22=1719/rec1501 (base), R23=1908(rev), R24=1786/rec1589(rev).

#define BB 32
#define TT 512
#define DD 300
#define UU 300
#define G4 1200   // 4*U
#define NTOK 3

#define KB   10    // rec blocks per direction
#define UPB  30    // units per rec block
#define NCOL 120   // gate-cols per rec block (4*UPB)
#define KTILES 10  // K = 320 (300 padded), 10 tiles of 32
#define HSTR 320   // swizzled LDS row stride (elems)
#define HROW 304   // global H row stride (elems)

#define WKROWS 1280  // WkT padded p-rows
#define WKSTR  320   // WkT padded k-stride

typedef uint16_t bf16_t;
typedef short  s16x8 __attribute__((ext_vector_type(8)));
typedef float  f32x4 __attribute__((ext_vector_type(4)));

union U8 { unsigned long long q[2]; s16x8 v; };

__device__ __forceinline__ float bf2f(uint16_t u) {
    union { uint32_t i; float f; } v; v.i = ((uint32_t)u) << 16; return v.f;
}
__device__ __forceinline__ uint16_t f2bf(float f) {
    union { uint32_t i; float f; } v; v.f = f;
    uint32_t r = v.i + 0x7fffu + ((v.i >> 16) & 1u);   // RNE
    return (uint16_t)(r >> 16);
}
__device__ __forceinline__ float ldf(const void* base, size_t idx, int f32m) {
    return f32m ? ((const float*)base)[idx]
                : bf2f(((const uint16_t*)base)[idx]);
}

// 4x4 transpose across lane bits 0..1 (verified R7)
__device__ __forceinline__ f32x4 xpose4(f32x4 v, int lane) {
    f32x4 t, w, s, r;
    t[0] = __shfl_xor(v[0], 1); t[1] = __shfl_xor(v[1], 1);
    t[2] = __shfl_xor(v[2], 1); t[3] = __shfl_xor(v[3], 1);
    if ((lane & 1) == 0) { w[0]=v[0]; w[1]=t[0]; w[2]=v[2]; w[3]=t[2]; }
    else                 { w[0]=t[1]; w[1]=v[1]; w[2]=t[3]; w[3]=v[3]; }
    s[0] = __shfl_xor(w[0], 2); s[1] = __shfl_xor(w[1], 2);
    s[2] = __shfl_xor(w[2], 2); s[3] = __shfl_xor(w[3], 2);
    if ((lane & 2) == 0) { r[0]=w[0]; r[1]=w[1]; r[2]=s[0]; r[3]=s[1]; }
    else                 { r[0]=s[2]; r[1]=s[3]; r[2]=w[2]; r[3]=w[3]; }
    return r;
}

// fast sigmoid/tanh: v_exp + v_rcp (rel err ~1e-6, margin 6x vs threshold)
__device__ __forceinline__ float fsig(float x) {
    return __builtin_amdgcn_rcpf(1.f + __expf(-x));
}
__device__ __forceinline__ float ftanh(float x) {
    float cx = fminf(10.f, fmaxf(-10.f, x));
    float e = __expf(2.f * cx);
    return (e - 1.f) * __builtin_amdgcn_rcpf(e + 1.f);
}

__device__ __forceinline__ void gatefn(f32x4 zv, uint2 zp, bool m,
                                       float& c, float& h) {
    float zi = zv[0] + bf2f((uint16_t)(zp.x & 0xffff));
    float zf = zv[1] + bf2f((uint16_t)(zp.x >> 16));
    float zg = zv[2] + bf2f((uint16_t)(zp.y & 0xffff));
    float zo = zv[3] + bf2f((uint16_t)(zp.y >> 16));
    float si = fsig(zi);
    float sf = fsig(zf);
    float so = fsig(zo);
    float tg = ftanh(zg);
    float cn = sf * c + si * tg;
    float hn = so * ftanh(cn);
    if (m) { c = cn; h = hn; }
}

// ---------------------------------------------------------------------------
// Kernel 0: dtype detector (f32 vs bf16 inputs).
// ---------------------------------------------------------------------------
__global__ void detect_dtype(const uint16_t* __restrict__ emb_u16,
                             int* __restrict__ flag) {
    __shared__ float red[256];
    const int tid = threadIdx.x;
    float m = 0.f;
    for (int k = tid; k < 4096; k += 256)
        m = fmaxf(m, fabsf(bf2f(emb_u16[2 * k])));
    red[tid] = m;
    __syncthreads();
    for (int s = 128; s > 0; s >>= 1) {
        if (tid < s) red[tid] = fmaxf(red[tid], red[tid + s]);
        __syncthreads();
    }
    if (tid == 0) flag[0] = (red[0] > 1.0e3f) ? 1 : 0;
}

// ---------------------------------------------------------------------------
// Kernel 1: build WrPT[dir][p][k] (rec weights): p = 4u+g, k-major rows of
// length 304 (k>=300 zero).  WrPT[p][k] = Wr[k][g*300+u].
// ---------------------------------------------------------------------------
__global__ void prep_wrp(const void* __restrict__ Wr_f,
                         const void* __restrict__ Wr_b,
                         bf16_t* __restrict__ WrPT_f,
                         bf16_t* __restrict__ WrPT_b,
                         const int* __restrict__ flagp) {
    const int f32m = *flagp;
    int idx = blockIdx.x * 256 + threadIdx.x;          // over 1200*304
    const void* src = blockIdx.y ? Wr_b : Wr_f;
    bf16_t*     dst = blockIdx.y ? WrPT_b : WrPT_f;
    if (idx < G4 * HROW) {
        int p = idx / HROW;
        int k = idx - p * HROW;
        int u = p >> 2, g = p & 3;
        float v = (k < DD) ? ldf(src, (size_t)k * G4 + g * UU + u, f32m) : 0.f;
        dst[idx] = f2bf(v);
    }
}

// ---------------------------------------------------------------------------
// Kernel 1c: build WkT[dir][p][k] (zx weights, permuted+padded) + biasP.
// ---------------------------------------------------------------------------
__global__ void prep_wkt(const void* __restrict__ Wk_f, const void* __restrict__ b_f,
                         const void* __restrict__ Wk_b, const void* __restrict__ b_b,
                         bf16_t* __restrict__ WkT, bf16_t* __restrict__ biasP,
                         const int* __restrict__ flagp) {
    const int f32m = *flagp;
    const int dir = blockIdx.y;
    const void* Wk = dir ? Wk_b : Wk_f;
    const void* bs = dir ? b_b  : b_f;
    bf16_t* dst = WkT + (size_t)dir * (WKROWS * WKSTR);
    int idx = blockIdx.x * 256 + threadIdx.x;          // over 1280*320
    if (idx < WKROWS * WKSTR) {
        int p = idx / WKSTR;
        int k = idx - p * WKSTR;
        int u = p >> 2, g = p & 3;
        float v = (p < G4 && k < DD) ? ldf(Wk, (size_t)k * G4 + g * UU + u, f32m)
                                     : 0.f;
        dst[idx] = f2bf(v);
        if (idx < WKROWS) {
            int pp = idx, uu = pp >> 2, gg = pp & 3;
            biasP[dir * WKROWS + idx] =
                (pp < G4) ? f2bf(ldf(bs, gg * UU + uu, f32m)) : (bf16_t)0;
        }
    }
}

// ---------------------------------------------------------------------------
// Kernel 1b: zero H double-buffers and ready flags.
// ---------------------------------------------------------------------------
__global__ void init_state(bf16_t* __restrict__ Hglob, int* __restrict__ flags) {
    int i = blockIdx.x * 256 + threadIdx.x;
    if (i < 2 * 2 * BB * HROW) Hglob[i] = 0;
    if (i < 2 * TT * 16) flags[i] = 0;
}

// ---------------------------------------------------------------------------
// Kernel 2: MFMA zx GEMM, A staged ONCE (R21-verbatim).
// ---------------------------------------------------------------------------
#define ZM 64
#define ZN 128
__global__ __launch_bounds__(256, 2) void zx_gemm3(
    const int* __restrict__ inputs, const void* __restrict__ emb,
    const bf16_t* __restrict__ WkTall, const bf16_t* __restrict__ biasP,
    bf16_t* __restrict__ zxf, bf16_t* __restrict__ zxb,
    const int* __restrict__ flagp) {

    const int f32m = *flagp;
    const int dir = blockIdx.y;
    const bf16_t* WkT = WkTall + (size_t)dir * (WKROWS * WKSTR);
    const bf16_t* bp  = biasP + dir * WKROWS;
    bf16_t* out = dir ? zxb : zxf;

    const int tid = threadIdx.x;
    const int rowBase = blockIdx.x * ZM;

    __shared__ __align__(16) uint16_t Alds[ZM * HSTR];   // 40,960 B
    __shared__ int rowids[ZM];

    if (tid < ZM) rowids[tid] = inputs[rowBase + tid];
    for (int i = tid; i < ZM * HSTR; i += 256) Alds[i] = 0;
    __syncthreads();

    // stage A gathered ONCE: 64 rows x 38 groups of 8, swizzled
    for (int i = tid; i < ZM * 38; i += 256) {
        int r = i / 38, g = i - 38 * r;
        int k0 = g * 8;
        const size_t eb = (size_t)rowids[r] * DD + k0;
        uint16_t tmp[8];
        if (g < 37) {
            if (f32m) {
                const float* ef = (const float*)emb + eb;
#pragma unroll
                for (int e = 0; e < 8; e++) tmp[e] = f2bf(ef[e]);
            } else {
                *(uint4*)tmp = *(const uint4*)((const uint16_t*)emb + eb);
            }
        } else {
#pragma unroll
            for (int e = 0; e < 8; e++) {
                int k = k0 + e;
                tmp[e] = (k < DD)
                    ? (f32m ? f2bf(((const float*)emb)[(size_t)rowids[r] * DD + k])
                            : ((const uint16_t*)emb)[(size_t)rowids[r] * DD + k])
                    : (uint16_t)0;
            }
        }
        *(uint4*)&Alds[r * HSTR + ((g ^ (r & 7)) << 3)] = *(uint4*)tmp;
    }
    __syncthreads();

    const int lane = tid & 63;
    const int wv   = tid >> 6;
    const int q    = lane >> 4;
    const int c16  = lane & 15;
    const int n0   = 32 * wv;
    const int sw7  = c16 & 7;
    const bool evn = ((lane & 1) == 0);

    for (int nt = 0; nt < 10; nt++) {
        const int pb = nt * ZN;
        const int p0 = pb + n0 + c16;
        const int p1 = p0 + 16;
        const float bv0 = bf2f(bp[p0]);
        const float bv1 = bf2f(bp[p1]);

        f32x4 acc[4][2];
#pragma unroll
        for (int mt = 0; mt < 4; mt++)
            for (int nh = 0; nh < 2; nh++) acc[mt][nh] = (f32x4){0.f,0.f,0.f,0.f};

#pragma unroll
        for (int kt = 0; kt < KTILES; kt++) {
            int k0 = 32 * kt + 8 * q;
            int sw = (((kt * 4 + q) ^ sw7) << 3);
            s16x8 b0 = *(const s16x8*)&WkT[(size_t)p0 * WKSTR + k0];
            s16x8 b1 = *(const s16x8*)&WkT[(size_t)p1 * WKSTR + k0];
#pragma unroll
            for (int mt = 0; mt < 4; mt++) {
                s16x8 af = *(const s16x8*)&Alds[(16 * mt + c16) * HSTR + sw];
                acc[mt][0] = __builtin_amdgcn_mfma_f32_16x16x32_bf16(af, b0, acc[mt][0], 0, 0, 0);
                acc[mt][1] = __builtin_amdgcn_mfma_f32_16x16x32_bf16(af, b1, acc[mt][1], 0, 0, 0);
            }
        }

        // epilogue: bias add, bf16, pair-pack via shfl_xor(1), even-lane u32
#pragma unroll
        for (int mt = 0; mt < 4; mt++) {
#pragma unroll
            for (int nh = 0; nh < 2; nh++) {
                const int p = (nh == 0) ? p0 : p1;
                const float bv = (nh == 0) ? bv0 : bv1;
#pragma unroll
                for (int r = 0; r < 4; r++) {
                    uint32_t mine = f2bf(acc[mt][nh][r] + bv);
                    uint32_t other = (uint32_t)__shfl_xor((int)mine, 1);
                    if (evn && p < G4) {
                        uint32_t pk = mine | (other << 16);
                        int row = rowBase + 16 * mt + 4 * q + r;
                        *(uint32_t*)&out[(size_t)row * G4 + p] = pk;
                    }
                }
            }
        }
    }
}

// ---------------------------------------------------------------------------
// Kernel 3: hybrid MFMA recurrence (R22-VERBATIM).  20 blocks, 256 thr.
// Fused speculative poll+H reload; hstage -> coalesced publish; 3 barriers.
// ---------------------------------------------------------------------------
__global__ __launch_bounds__(256, 1) void lstm_rec4(
    const bf16_t* __restrict__ zxf, const bf16_t* __restrict__ zxb,
    const bf16_t* __restrict__ WrPT_f, const bf16_t* __restrict__ WrPT_b,
    const int* __restrict__ seqlen,
    bf16_t* __restrict__ Hglob, int* __restrict__ flags,
    bf16_t* __restrict__ hf, bf16_t* __restrict__ hb) {

    const int blk = blockIdx.x % KB;
    const int dir = blockIdx.x / KB;
    const bf16_t* zx   = dir ? zxb    : zxf;
    const bf16_t* WrPT = dir ? WrPT_b : WrPT_f;
    bf16_t*       hout = dir ? hb : hf;
    bf16_t*       Hg   = Hglob + (size_t)dir * (2 * BB * HROW);
    int*          fbase = flags + dir * (TT * 16);

    __shared__ __align__(16) uint16_t Hlds[BB * HSTR];    // 20,480 B
    __shared__ uint16_t hstage[BB * UPB];                 //  1,920 B

    const int tid  = threadIdx.x;
    const int lane = tid & 63;
    const int wv   = tid >> 6;
    const int q    = lane >> 4;
    const int c16  = lane & 15;
    const int n0   = 32 * wv;
    const int sw7  = c16 & 7;
    const int k4   = c16 >> 2;
    const int j4   = c16 & 3;
    const int u0   = 8 * wv + k4;
    const int b0   = 4 * q + j4;
    const bool v1  = (u0 + 4 < UPB);
    const bool pollme = (lane < KB) && (lane != blk);

    // one-time: zero Hlds (pad groups 38,39 must read 0), B-frags to regs
    for (int i = tid; i < BB * HSTR; i += 256) Hlds[i] = 0;
    U8 Bf0[KTILES], Bf1[KTILES];
#pragma unroll
    for (int kt = 0; kt < KTILES; kt++) {
        int k0 = 32 * kt + 8 * q;
        int col0 = n0 + c16, col1 = n0 + 16 + c16;
        U8 z; z.q[0] = 0; z.q[1] = 0;
        Bf0[kt] = z; Bf1[kt] = z;
        if (k0 < 304) {
            if (col0 < NCOL)
                Bf0[kt].v = *(const s16x8*)&WrPT[(size_t)(NCOL * blk + col0) * HROW + k0];
            if (col1 < NCOL)
                Bf1[kt].v = *(const s16x8*)&WrPT[(size_t)(NCOL * blk + col1) * HROW + k0];
        }
    }
    float c00 = 0.f, c01 = 0.f, c10 = 0.f, c11 = 0.f;
    float h00 = 0.f, h01 = 0.f, h10 = 0.f, h11 = 0.f;
    const int L0 = seqlen[b0];
    const int L1 = seqlen[b0 + 16];
    __syncthreads();

    for (int ts = 0; ts < TT; ts++) {
        const int t = dir ? (TT - 1 - ts) : ts;

        // zx prefetch (overlaps the flag wait)
        const size_t zr0 = ((size_t)(b0 * TT + t)) * G4 + NCOL * blk;
        const size_t zr1 = ((size_t)((b0 + 16) * TT + t)) * G4 + NCOL * blk;
        uint2 z00 = *(const uint2*)&zx[zr0 + 4 * u0];
        uint2 z10 = *(const uint2*)&zx[zr1 + 4 * u0];
        uint2 z01 = {0, 0}, z11 = {0, 0};
        if (v1) {
            z01 = *(const uint2*)&zx[zr0 + 4 * (u0 + 4)];
            z11 = *(const uint2*)&zx[zr1 + 4 * (u0 + 4)];
        }

        // fused poll + speculative H reload:
        // flag sample issued FIRST, H loads issued right behind it; if the
        // sample shows all-set, the H loads are valid (payload acks drained
        // >= RT/2 before the flag store departed the producer).
        const unsigned long long* Hsrc64 =
            (const unsigned long long*)(Hg + (size_t)(ts & 1) * (BB * HROW));
        unsigned long long hv[10];
        if (ts > 0) {
            int* fl = fbase + (ts - 1) * 16;
            for (;;) {
                int a = pollme ? __hip_atomic_load(&fl[lane], __ATOMIC_RELAXED,
                                                   __HIP_MEMORY_SCOPE_AGENT) : 1;
                asm volatile("" ::: "memory");          // pin flag->H issue order (IR)
                __builtin_amdgcn_sched_barrier(0);      // pin at MIR level too
#pragma unroll
                for (int k = 0; k < 9; k++)
                    hv[k] = __hip_atomic_load(&Hsrc64[tid + 256 * k],
                                              __ATOMIC_RELAXED,
                                              __HIP_MEMORY_SCOPE_AGENT);
                if (tid < 128)
                    hv[9] = __hip_atomic_load(&Hsrc64[2304 + tid],
                                              __ATOMIC_RELAXED,
                                              __HIP_MEMORY_SCOPE_AGENT);
                if (__all(a != 0)) break;
            }
        } else {
#pragma unroll
            for (int k = 0; k < 9; k++)
                hv[k] = __hip_atomic_load(&Hsrc64[tid + 256 * k],
                                          __ATOMIC_RELAXED,
                                          __HIP_MEMORY_SCOPE_AGENT);
            if (tid < 128)
                hv[9] = __hip_atomic_load(&Hsrc64[2304 + tid],
                                          __ATOMIC_RELAXED,
                                          __HIP_MEMORY_SCOPE_AGENT);
        }
#pragma unroll
        for (int k = 0; k < 9; k++) {
            int i = tid + 256 * k;
            int b = i / 76, x = i - 76 * b;
            *(unsigned long long*)
                &Hlds[b * HSTR + ((((x >> 1) ^ (b & 7)) << 3) | ((x & 1) << 2))]
                = hv[k];
        }
        if (tid < 128) {
            int i = 2304 + tid;
            int b = i / 76, x = i - 76 * b;
            *(unsigned long long*)
                &Hlds[b * HSTR + ((((x >> 1) ^ (b & 7)) << 3) | ((x & 1) << 2))]
                = hv[9];
        }
        __syncthreads();                                  // (1)

        // MFMA: A from Hlds (swizzled), B from registers
        f32x4 acc00 = {0.f,0.f,0.f,0.f}, acc01 = {0.f,0.f,0.f,0.f};
        f32x4 acc10 = {0.f,0.f,0.f,0.f}, acc11 = {0.f,0.f,0.f,0.f};
#pragma unroll
        for (int kt = 0; kt < KTILES; kt++) {
            int sw = (((kt * 4 + q) ^ sw7) << 3);
            s16x8 a0 = *(const s16x8*)&Hlds[c16 * HSTR + sw];
            s16x8 a1 = *(const s16x8*)&Hlds[(c16 + 16) * HSTR + sw];
            acc00 = __builtin_amdgcn_mfma_f32_16x16x32_bf16(a0, Bf0[kt].v, acc00, 0, 0, 0);
            acc01 = __builtin_amdgcn_mfma_f32_16x16x32_bf16(a0, Bf1[kt].v, acc01, 0, 0, 0);
            acc10 = __builtin_amdgcn_mfma_f32_16x16x32_bf16(a1, Bf0[kt].v, acc10, 0, 0, 0);
            acc11 = __builtin_amdgcn_mfma_f32_16x16x32_bf16(a1, Bf1[kt].v, acc11, 0, 0, 0);
        }

        // transpose + gates in registers (R7-verified mapping)
        f32x4 t00 = xpose4(acc00, lane);
        f32x4 t01 = xpose4(acc01, lane);
        f32x4 t10 = xpose4(acc10, lane);
        f32x4 t11 = xpose4(acc11, lane);
        const bool m0 = (t < L0);
        const bool m1 = (t < L1);
        gatefn(t00, z00, m0, c00, h00);
        gatefn(t01, z01, m0, c01, h01);
        gatefn(t10, z10, m1, c10, h10);
        gatefn(t11, z11, m1, c11, h11);

        hstage[b0 * UPB + u0]        = f2bf(h00);
        hstage[(b0 + 16) * UPB + u0] = f2bf(h10);
        if (v1) {
            hstage[b0 * UPB + u0 + 4]        = f2bf(h01);
            hstage[(b0 + 16) * UPB + u0 + 4] = f2bf(h11);
        }
        __syncthreads();                                  // (2)

        if (ts < TT - 1) {
            bf16_t* Hdst = Hg + (size_t)((ts + 1) & 1) * (BB * HROW);
            for (int i = tid; i < BB * (UPB / 2); i += 256) {   // 480 pairs
                int b = i / (UPB / 2), k = i - b * (UPB / 2);
                uint32_t val = (uint32_t)hstage[b * UPB + 2 * k] |
                               ((uint32_t)hstage[b * UPB + 2 * k + 1] << 16);
                __hip_atomic_store(
                    (uint32_t*)&Hdst[b * HROW + UPB * blk + 2 * k], val,
                    __ATOMIC_RELAXED, __HIP_MEMORY_SCOPE_AGENT);
            }
            __syncthreads();                              // (3) drain
            if (tid == 0)
                __hip_atomic_store(&fbase[ts * 16 + blk], 1, __ATOMIC_RELAXED,
                                   __HIP_MEMORY_SCOPE_AGENT);
        }

        // private hout stores, off the critical path (coalesced from hstage)
        for (int i = tid; i < BB * (UPB / 2); i += 256) {
            int b = i / (UPB / 2), k = i - b * (UPB / 2);
            uint32_t val = (uint32_t)hstage[b * UPB + 2 * k] |
                           ((uint32_t)hstage[b * UPB + 2 * k + 1] << 16);
            *(uint32_t*)&hout[((size_t)(b * TT + t)) * UU + UPB * blk + 2 * k] = val;
        }
    }
}

// ---------------------------------------------------------------------------
// Kernel 4: out[r] = [hf[r] ; hb[r]] @ fc_W + fc_b.  (vectorized h loads)
// ---------------------------------------------------------------------------
__global__ __launch_bounds__(256) void fc_out(
    const bf16_t* __restrict__ hf, const bf16_t* __restrict__ hb,
    const void* __restrict__ fcW, const void* __restrict__ fcb,
    void* __restrict__ out, const int* __restrict__ flagp) {

    const int f32m = *flagp;
    __shared__ float W[2 * UU * NTOK];
    __shared__ float bias[NTOK];
    const int tid = threadIdx.x;
    for (int i = tid; i < 2 * UU * NTOK; i += 256) W[i] = ldf(fcW, i, f32m);
    if (tid < NTOK) bias[tid] = ldf(fcb, tid, f32m);
    __syncthreads();

    const int r = blockIdx.x * 256 + tid;
    const bf16_t* hfr = hf + (size_t)r * UU;
    const bf16_t* hbr = hb + (size_t)r * UU;
    float s0 = bias[0], s1 = bias[1], s2 = bias[2];
#pragma unroll 5
    for (int g = 0; g < UU / 4; g++) {          // 75 uint2 loads (4 bf16 each)
        uint2 v = *(const uint2*)&hfr[g * 4];
        const float* Wp = &W[g * 12];
#pragma unroll
        for (int e = 0; e < 4; e++) {
            uint32_t w = (e < 2) ? v.x : v.y;
            float f = bf2f((uint16_t)((e & 1) ? (w >> 16) : (w & 0xffff)));
            s0 += f * Wp[e * 3 + 0];
            s1 += f * Wp[e * 3 + 1];
            s2 += f * Wp[e * 3 + 2];
        }
    }
#pragma unroll 5
    for (int g = 0; g < UU / 4; g++) {
        uint2 v = *(const uint2*)&hbr[g * 4];
        const float* Wp = &W[(UU + g * 4) * 3];
#pragma unroll
        for (int e = 0; e < 4; e++) {
            uint32_t w = (e < 2) ? v.x : v.y;
            float f = bf2f((uint16_t)((e & 1) ? (w >> 16) : (w & 0xffff)));
            s0 += f * Wp[e * 3 + 0];
            s1 += f * Wp[e * 3 + 1];
            s2 += f * Wp[e * 3 + 2];
        }
    }
    if (f32m) {
        float* o = (float*)out;
        o[(size_t)r * 3 + 0] = s0;
        o[(size_t)r * 3 + 1] = s1;
        o[(size_t)r * 3 + 2] = s2;
    } else {
        bf16_t* o = (bf16_t*)out;
        o[(size_t)r * 3 + 0] = f2bf(s0);
        o[(size_t)r * 3 + 1] = f2bf(s1);
        o[(size_t)r * 3 + 2] = f2bf(s2);
    }
}

// ---------------------------------------------------------------------------
extern "C" void kernel_launch(void* const* d_in, const int* in_sizes, int n_in,
                              void* d_out, int out_size, void* d_ws, size_t ws_size,
                              hipStream_t stream) {
    const int* inputs = (const int*)d_in[0];
    const int* seqlen = (const int*)d_in[1];
    const void* emb  = d_in[2];
    const void* Wk_f = d_in[3];
    const void* Wr_f = d_in[4];
    const void* b_f  = d_in[5];
    const void* Wk_b = d_in[6];
    const void* Wr_b = d_in[7];
    const void* b_b  = d_in[8];
    const void* fcW  = d_in[9];
    const void* fcb  = d_in[10];

    // workspace layout (bytes)
    char* ws = (char*)d_ws;
    int*    flag   = (int*)(ws + 0);                 // 64 B
    int*    flags  = (int*)(ws + 64);                // 65,536
    bf16_t* Hglob  = (bf16_t*)(ws + 65664);          // 77,824
    bf16_t* WrPT_f = (bf16_t*)(ws + 143488);         // 729,600
    bf16_t* WrPT_b = (bf16_t*)(ws + 873088);         // 729,600
    bf16_t* zxPf   = (bf16_t*)(ws + 1602688);        // 39,321,600
    bf16_t* zxPb   = (bf16_t*)(ws + 40924288);       // 39,321,600
    bf16_t* hfbuf  = (bf16_t*)(ws + 80245888);       // 9,830,400
    bf16_t* hbbuf  = (bf16_t*)(ws + 90076288);       // 9,830,400 -> 99,906,688
    // WkT/biasP alias hfbuf: consumed by zx_gemm3 (before rec), clobbered by rec
    bf16_t* WkT    = hfbuf;                          // 2*1280*320*2 = 1,638,400
    bf16_t* biasP  = hfbuf + 2 * WKROWS * WKSTR;     // 5,120

    detect_dtype<<<1, 256, 0, stream>>>((const uint16_t*)emb, flag);
    {
        dim3 grid((G4 * HROW + 255) / 256, 2);
        prep_wrp<<<grid, 256, 0, stream>>>(Wr_f, Wr_b, WrPT_f, WrPT_b, flag);
    }
    {
        dim3 grid((WKROWS * WKSTR + 255) / 256, 2);
        prep_wkt<<<grid, 256, 0, stream>>>(Wk_f, b_f, Wk_b, b_b, WkT, biasP, flag);
    }
    init_state<<<64, 256, 0, stream>>>(Hglob, flags);
    {
        dim3 grid(256, 2);
        zx_gemm3<<<grid, 256, 0, stream>>>(inputs, emb, WkT, biasP,
                                           zxPf, zxPb, flag);
    }
    lstm_rec4<<<2 * KB, 256, 0, stream>>>(zxPf, zxPb, WrPT_f, WrPT_b, seqlen,
                                          Hglob, flags, hfbuf, hbbuf);
    fc_out<<<(BB * TT) / 256, 256, 0, stream>>>(hfbuf, hbbuf, fcW, fcb,
                                                d_out, flag);
}